// Round 1
// baseline (1203.485 us; speedup 1.0000x reference)
//
#include <hip/hip_runtime.h>

#define N_IN 8192
#define N_OUT 8192

// ---------------------------------------------------------------------------
// K1: per-input-neuron prep. Computes the tiny 3-wide bud MLP front half
// (h2[k][0..2]) which depends ONLY on x[k], plus the active flag
// (saturated && x!=0) and x_masked for the dense part. 8192 threads total.
// ---------------------------------------------------------------------------
__global__ __launch_bounds__(256) void k1_prep(
    const float* __restrict__ x, const int* __restrict__ sat,
    const float* __restrict__ W1, const float* __restrict__ b1,
    const float* __restrict__ W2, const float* __restrict__ b2,
    float4* __restrict__ h2buf, float* __restrict__ xmbuf)
{
    int k = blockIdx.x * blockDim.x + threadIdx.x;
    if (k >= N_IN) return;
    float xs = x[k];
    bool s = (sat[k] != 0);
    xmbuf[k] = s ? 0.0f : xs;   // x * (1 - sat_f)

    const float* w1 = W1 + (size_t)k * 9;
    const float* B1 = b1 + (size_t)k * 3;
    float x3 = xs * (1.0f / 3.0f);
    float h1[3];
#pragma unroll
    for (int i = 0; i < 3; ++i) {
        float v = x3 * (w1[3*i] + w1[3*i+1] + w1[3*i+2]) + B1[i];
        h1[i] = v > 0.0f ? v : 0.0f;
    }
    const float* w2 = W2 + (size_t)k * 9;
    const float* B2 = b2 + (size_t)k * 3;
    float h2[3];
#pragma unroll
    for (int i = 0; i < 3; ++i) {
        float v = w2[3*i] * h1[0] + w2[3*i+1] * h1[1] + w2[3*i+2] * h1[2] + B2[i];
        h2[i] = v > 0.0f ? v : 0.0f;
    }
    float flag = (s && xs != 0.0f) ? 1.0f : 0.0f;
    h2buf[k] = make_float4(h2[0], h2[1], h2[2], flag);
}

// ---------------------------------------------------------------------------
// K2: dense matvec out[o] = bias[o] + dot(weight[o,:], x_masked).
// One wave (64 lanes) per output row; float4 coalesced weight reads
// (1 KiB / wave / iteration). 4 waves per block, 2048 blocks.
// ---------------------------------------------------------------------------
__global__ __launch_bounds__(256) void k2_dense(
    const float* __restrict__ weight, const float* __restrict__ bias,
    const float* __restrict__ xm, float* __restrict__ out)
{
    int wave = threadIdx.x >> 6;
    int lane = threadIdx.x & 63;
    int o = blockIdx.x * 4 + wave;

    const float4* wrow = (const float4*)(weight + (size_t)o * N_IN);
    const float4* xv   = (const float4*)xm;

    float sum = 0.0f;
#pragma unroll 4
    for (int it = 0; it < N_IN / 4 / 64; ++it) {   // 32 iters
        int idx = it * 64 + lane;
        float4 w = wrow[idx];
        float4 v = xv[idx];
        sum += w.x * v.x + w.y * v.y + w.z * v.z + w.w * v.w;
    }
#pragma unroll
    for (int off = 32; off; off >>= 1) sum += __shfl_down(sum, off);
    if (lane == 0) out[o] = bias[o] + sum;
}

// ---------------------------------------------------------------------------
// K3: bud accumulation u[o] += relu(h2[k]·W3[k,o,:] + b3[k,o]) for active k.
// Grid = 8 o-tiles (1024 outputs each) x 128 k-chunks (64 k each) = 1024
// blocks. Each thread owns 4 contiguous o -> W3 row slice is 3 aligned
// float4s, b3 one float4. Inactive k skipped wave-uniformly (flag is the
// same for the whole block), which skips the HBM reads for that row.
// Partial sums land in out via hw fp32 atomics (stream-ordered after K2).
// ---------------------------------------------------------------------------
__global__ __launch_bounds__(256) void k3_bud(
    const float* __restrict__ W3, const float* __restrict__ b3,
    const float4* __restrict__ h2buf, float* __restrict__ out)
{
    int otile  = blockIdx.x & 7;    // 8 tiles of 1024 outputs
    int kchunk = blockIdx.x >> 3;   // 128 chunks of 64 inputs
    int o  = otile * 1024 + threadIdx.x * 4;
    int k0 = kchunk * 64;

    float acc0 = 0.0f, acc1 = 0.0f, acc2 = 0.0f, acc3 = 0.0f;

    for (int kk = 0; kk < 64; ++kk) {
        int k = k0 + kk;
        float4 h = h2buf[k];            // broadcast load, L1/L2-resident
        if (h.w == 0.0f) continue;      // wave-uniform skip: no W3/b3 traffic

        const float4* wp = (const float4*)(W3 + ((size_t)k * N_OUT + o) * 3);
        float4 a = wp[0], b = wp[1], c = wp[2];
        float4 bb = *(const float4*)(b3 + (size_t)k * N_OUT + o);

        float t0 = h.x * a.x + h.y * a.y + h.z * a.z + bb.x;
        float t1 = h.x * a.w + h.y * b.x + h.z * b.y + bb.y;
        float t2 = h.x * b.z + h.y * b.w + h.z * c.x + bb.z;
        float t3 = h.x * c.y + h.y * c.z + h.z * c.w + bb.w;
        acc0 += t0 > 0.0f ? t0 : 0.0f;
        acc1 += t1 > 0.0f ? t1 : 0.0f;
        acc2 += t2 > 0.0f ? t2 : 0.0f;
        acc3 += t3 > 0.0f ? t3 : 0.0f;
    }

    unsafeAtomicAdd(out + o + 0, acc0);   // global_atomic_add_f32
    unsafeAtomicAdd(out + o + 1, acc1);
    unsafeAtomicAdd(out + o + 2, acc2);
    unsafeAtomicAdd(out + o + 3, acc3);
}

extern "C" void kernel_launch(void* const* d_in, const int* in_sizes, int n_in,
                              void* d_out, int out_size, void* d_ws, size_t ws_size,
                              hipStream_t stream)
{
    const float* x    = (const float*)d_in[0];
    const int*   sat  = (const int*)  d_in[1];
    const float* wgt  = (const float*)d_in[2];
    const float* bias = (const float*)d_in[3];
    const float* W1   = (const float*)d_in[4];
    const float* b1   = (const float*)d_in[5];
    const float* W2   = (const float*)d_in[6];
    const float* b2   = (const float*)d_in[7];
    const float* W3   = (const float*)d_in[8];
    const float* b3   = (const float*)d_in[9];
    float* out = (float*)d_out;

    float4* h2buf = (float4*)d_ws;                                   // 128 KiB
    float*  xmbuf = (float*)((char*)d_ws + N_IN * sizeof(float4));   // +32 KiB

    k1_prep<<<N_IN / 256, 256, 0, stream>>>(x, sat, W1, b1, W2, b2, h2buf, xmbuf);
    k2_dense<<<N_OUT / 4, 256, 0, stream>>>(wgt, bias, xmbuf, out);
    k3_bud<<<1024, 256, 0, stream>>>(W3, b3, h2buf, out);
}